// Round 13
// baseline (223.831 us; speedup 1.0000x reference)
//
#include <hip/hip_runtime.h>
#include <hip/hip_fp16.h>

// ---------------------------------------------------------------------------
// IN=128, H=8, R=16, D=16 -> H*R = H*D = 128
// K = h @ q, Q = h @ p, V = h @ Wv   (K uses weight "q", Q uses weight "p")
// score = exp(clip((K[src]*Q[dst]).sum(r)/4, -5, 5))
// out = seg_sum(score*V[src], dst) / max(seg_sum(score,dst), eps-fixup)
//
// R13: head-per-XCD aggregation (head = blockIdx&7): 3.2MB/head fits XCD L2.
// R15/R16: node-parallel quad-per-edge aggregate: ~89us floor (validated by
//      multiple nulls; scattered-64B L2 line-service roofline ~83us).
// R17/R19 (FAILED): per-edge atomics (global OR LDS same-address). Banned.
// R18 (FAILED): per-head sort replication. Sort once per edge.
// R20 (=R8, BEST 214us): gcsr reservation scatter + fine2 + R16 aggregate.
// R22/R23/R24: three single-variable probes of D1 (delete scatter compute /
//      cut atomic contention / scatter-first order) ALL null-or-negative.
//      Bottom-up model of D1 (~50us) is ~50us short of observed front-end.
//      Model and measurement disagree -> MEASURE.
// R25 (this): DIAGNOSTIC SPLIT. D1's two branches become separate kernels
//      (byte-identical bodies). Next profile shows per-phase dur/counters for
//      gemm vs scatter vs fine2 vs gaps, and tests the overlap premise of
//      the mixed dispatch. Order: D0, scatter, fine2, gemm, aggregate.
// ---------------------------------------------------------------------------

#define HNODE 64        // nodes per GEMM block
#define EPB   4096      // edges per scatter block
#define BKT_SHIFT 7     // 128 nodes per bucket
#define BKT_CAP 5120    // bucket mean 4092 + 16 sigma

typedef _Float16 f16x8 __attribute__((ext_vector_type(8)));
typedef float    f32x4 __attribute__((ext_vector_type(4)));
typedef _Float16 hv2   __attribute__((ext_vector_type(2)));

__device__ __forceinline__ float fdot2(unsigned a, unsigned b, float c) {
#if __has_builtin(__builtin_amdgcn_fdot2)
    return __builtin_amdgcn_fdot2(__builtin_bit_cast(hv2, a),
                                  __builtin_bit_cast(hv2, b), c, false);
#else
    __half2 ah = *(__half2*)&a, bh = *(__half2*)&b;
    float2 af = __half22float2(ah), bf = __half22float2(bh);
    return c + af.x * bf.x + af.y * bf.y;
#endif
}

__device__ __forceinline__ float2 h2f(unsigned u) {
    __half2 hh = *(__half2*)&u;
    return __half22float2(hh);
}

__device__ __forceinline__ unsigned pack2(float a, float b) {
    __half2 hh = __floats2half2_rn(a, b);
    return *(unsigned*)&hh;
}

__device__ __forceinline__ float clamp5(float x) {
#if __has_builtin(__builtin_amdgcn_fmed3f)
    return __builtin_amdgcn_fmed3f(x, -5.f, 5.f);   // v_med3_f32 = clamp idiom
#else
    return fminf(fmaxf(x, -5.f), 5.f);
#endif
}

// ---- quad-scope cross-lane via DPP (VALU pipe, no LDS traffic) -------------
#if __has_builtin(__builtin_amdgcn_mov_dpp)
#define QBCAST(v, J) __builtin_amdgcn_mov_dpp((v), (J) * 0x55, 0xF, 0xF, true)
__device__ __forceinline__ float qadd_xor1(float x) {
    int y = __builtin_amdgcn_mov_dpp(__float_as_int(x), 0xB1, 0xF, 0xF, true);
    return x + __int_as_float(y);
}
__device__ __forceinline__ float qadd_xor2(float x) {
    int y = __builtin_amdgcn_mov_dpp(__float_as_int(x), 0x4E, 0xF, 0xF, true);
    return x + __int_as_float(y);
}
#else
#define QBCAST(v, J) __shfl((v), ((threadIdx.x & 63) & ~3) + (J), 64)
__device__ __forceinline__ float qadd_xor1(float x) { return x + __shfl_xor(x, 1); }
__device__ __forceinline__ float qadd_xor2(float x) { return x + __shfl_xor(x, 2); }
#endif

// ---------------- D0: weight transpose+convert + zero bucket totals ---------
__global__ __launch_bounds__(256) void wt_convert_kernel(
    const float* __restrict__ Wq, const float* __restrict__ Wp,
    const float* __restrict__ Wv, __half* __restrict__ Wt,
    int* __restrict__ btot, int nbkt)
{
    int o = blockIdx.x * 256 + threadIdx.x;
    if (o < 49152) {                               // 3*128*128 weights
        int m = o >> 14, rem = o & 16383;
        int nn = rem >> 7, kk = rem & 127;
        const float* W = (m == 0) ? Wq : (m == 1) ? Wp : Wv;
        Wt[o] = __float2half(W[kk * 128 + nn]);
    } else {
        int i = o - 49152;
        if (i < nbkt) btot[i] = 0;
    }
}

// ---------------- D1a: scatter (R8 branch, standalone) ----------------------
// LDS bucket sort, ONE global atomicAdd per (block,bucket) reservation,
// coalesced run copy into gcsr.
__global__ __launch_bounds__(256) void scatter_kernel(
    const int* __restrict__ src, const int* __restrict__ dst,
    unsigned* __restrict__ gcsr, int* __restrict__ btot,
    int E, int nbkt)
{
    __shared__ __align__(16) char smem[39936];
    const int t = threadIdx.x;

    unsigned long long* sorted = (unsigned long long*)smem;   // 4096 (32KB)
    int* cnt  = (int*)(smem + 32768);                         // 512
    int* lofs = (int*)(smem + 34816);                         // 512
    int* ts   = (int*)(smem + 36864);                         // 256
    int* base_sh = (int*)(smem + 37888);                      // 512

    int blk = blockIdx.x;
    for (int i = t; i < 512; i += 256) cnt[i] = 0;
    __syncthreads();

    int4 sv[4], dv[4], rk[4];
    int base = blk * EPB + t * 4;
    #pragma unroll
    for (int r = 0; r < 4; r++) {
        int i = base + r * 1024;
        if (i + 3 < E) {
            sv[r] = *(const int4*)(src + i);
            dv[r] = *(const int4*)(dst + i);
        } else {
            int tsrc[4], tdst[4];
            for (int k = 0; k < 4; k++) {
                int j = i + k;
                tsrc[k] = (j < E) ? src[j] : 0;
                tdst[k] = (j < E) ? dst[j] : -1;
            }
            sv[r] = make_int4(tsrc[0], tsrc[1], tsrc[2], tsrc[3]);
            dv[r] = make_int4(tdst[0], tdst[1], tdst[2], tdst[3]);
        }
        rk[r].x = (dv[r].x >= 0) ? atomicAdd(&cnt[dv[r].x >> BKT_SHIFT], 1) : 0;
        rk[r].y = (dv[r].y >= 0) ? atomicAdd(&cnt[dv[r].y >> BKT_SHIFT], 1) : 0;
        rk[r].z = (dv[r].z >= 0) ? atomicAdd(&cnt[dv[r].z >> BKT_SHIFT], 1) : 0;
        rk[r].w = (dv[r].w >= 0) ? atomicAdd(&cnt[dv[r].w >> BKT_SHIFT], 1) : 0;
    }
    __syncthreads();

    // exclusive scan over 512 bucket counts (thread t owns 2t, 2t+1)
    int c0 = cnt[2 * t], c1 = cnt[2 * t + 1];
    int ps = c0 + c1;
    ts[t] = ps; __syncthreads();
    for (int off = 1; off < 256; off <<= 1) {
        int x = ts[t];
        int y = (t >= off) ? ts[t - off] : 0;
        __syncthreads();
        ts[t] = x + y;
        __syncthreads();
    }
    int pbase = ts[t] - ps;
    lofs[2 * t] = pbase;
    lofs[2 * t + 1] = pbase + c0;

    // reserve contiguous gcsr ranges: ONE global atomic per nonzero bucket
    for (int i = t; i < nbkt; i += 256) {
        int c = cnt[i];
        base_sh[i] = (c > 0) ? atomicAdd(&btot[i], c) : 0;
    }
    __syncthreads();

    #pragma unroll
    for (int r = 0; r < 4; r++) {
        int s, d;
        d = dv[r].x; if (d >= 0) { s = sv[r].x; sorted[lofs[d >> BKT_SHIFT] + rk[r].x] = ((unsigned long long)d << 18) | (unsigned)s; }
        d = dv[r].y; if (d >= 0) { s = sv[r].y; sorted[lofs[d >> BKT_SHIFT] + rk[r].y] = ((unsigned long long)d << 18) | (unsigned)s; }
        d = dv[r].z; if (d >= 0) { s = sv[r].z; sorted[lofs[d >> BKT_SHIFT] + rk[r].z] = ((unsigned long long)d << 18) | (unsigned)s; }
        d = dv[r].w; if (d >= 0) { s = sv[r].w; sorted[lofs[d >> BKT_SHIFT] + rk[r].w] = ((unsigned long long)d << 18) | (unsigned)s; }
    }
    __syncthreads();

    int tot = ts[255];
    #pragma unroll
    for (int j = 0; j < 16; j++) {
        int i = j * 256 + t;
        if (i < tot) {
            unsigned long long e = sorted[i];
            int d = (int)(e >> 18);
            int b = d >> BKT_SHIFT;
            int k = i - lofs[b];
            int pos = base_sh[b] + k;
            if (pos < BKT_CAP)
                gcsr[(size_t)b * BKT_CAP + pos] =
                    ((unsigned)(d & 127) << 18) | (unsigned)(e & 0x3FFFFu);
        }
    }
}

// ---------------- D1b: GEMM (R8 branch, standalone) -------------------------
__global__ __launch_bounds__(256) void gemm_kernel(
    const float* __restrict__ h, const __half* __restrict__ Wt,
    unsigned* __restrict__ KV, __half* __restrict__ Q, int n)
{
    __shared__ __align__(16) char smem[34816];
    const int t = threadIdx.x;

    _Float16* ws = (_Float16*)smem;            // 128 x 136 halves
    const int wid = t >> 6, lane = t & 63;
    const int node0 = blockIdx.x * HNODE;
    const int mrow = lane & 15, quad = lane >> 4;

    const int row = node0 + wid * 16 + mrow;
    const bool rowvalid = (row < n);
    const int rowc = rowvalid ? row : (n - 1);

    f16x8 hfr[4];
    #pragma unroll
    for (int s = 0; s < 4; s++) {
        const float4* hp = (const float4*)(h + (size_t)rowc * 128 + quad * 8 + 32 * s);
        float4 f0 = hp[0], f1 = hp[1];
        f16x8 a;
        a[0] = (_Float16)f0.x; a[1] = (_Float16)f0.y;
        a[2] = (_Float16)f0.z; a[3] = (_Float16)f0.w;
        a[4] = (_Float16)f1.x; a[5] = (_Float16)f1.y;
        a[6] = (_Float16)f1.z; a[7] = (_Float16)f1.w;
        hfr[s] = a;
    }

    f32x4 acc[3][8];
    #pragma unroll
    for (int m = 0; m < 3; m++)
        #pragma unroll
        for (int ct = 0; ct < 8; ct++) acc[m][ct] = (f32x4){0.f, 0.f, 0.f, 0.f};

    #pragma unroll
    for (int m = 0; m < 3; m++) {
        __syncthreads();
        {
            const uint4* wg = (const uint4*)(Wt + (size_t)m * 16384);
            #pragma unroll
            for (int i = 0; i < 8; i++) {
                int idx = t * 8 + i;            // 0..2047
                int r = idx >> 4, seg = idx & 15;
                *(uint4*)(ws + r * 136 + seg * 8) = wg[idx];
            }
        }
        __syncthreads();
        #pragma unroll
        for (int s = 0; s < 4; s++) {
            #pragma unroll
            for (int ct = 0; ct < 8; ct++) {
                f16x8 a = *(const f16x8*)(ws + (ct * 16 + mrow) * 136 + quad * 8 + 32 * s);
                acc[m][ct] = __builtin_amdgcn_mfma_f32_16x16x32_f16(a, hfr[s], acc[m][ct], 0, 0, 0);
            }
        }
    }

    if (rowvalid) {
        // head-major epilogue: for MFMA tile ct, head = ct, quarter = quad
        #pragma unroll
        for (int ct = 0; ct < 8; ct++) {
            uint4 ov;
            ov.x = pack2(acc[0][ct][0], acc[0][ct][1]);   // K pair
            ov.y = pack2(acc[0][ct][2], acc[0][ct][3]);
            ov.z = pack2(acc[2][ct][0], acc[2][ct][1]);   // V pair
            ov.w = pack2(acc[2][ct][2], acc[2][ct][3]);
            *(uint4*)(KV + (((size_t)ct * n + row) << 4) + 4 * quad) = ov;
            uint2 qv;
            qv.x = pack2(acc[1][ct][0], acc[1][ct][1]);
            qv.y = pack2(acc[1][ct][2], acc[1][ct][3]);
            *(uint2*)(Q + (((size_t)ct * n + row) << 4) + 4 * quad) = qv;
        }
    }
}

// ---------------- D2: per-bucket CSR from contiguous gcsr (R8 version) ------
__global__ __launch_bounds__(512) void fine2_kernel(
    const unsigned* __restrict__ gcsr, const int* __restrict__ btot,
    int2* __restrict__ offs, unsigned short* __restrict__ csr,
    int* __restrict__ nodeord, int N)
{
    __shared__ unsigned sedge[BKT_CAP];
    __shared__ unsigned short srank[BKT_CAP];
    __shared__ unsigned short lcsr[BKT_CAP];
    __shared__ int ldeg[128];
    __shared__ int lstart[128];
    __shared__ int ts[128];

    const int b = blockIdx.x, t = threadIdx.x;
    const int seg0 = b * BKT_CAP;

    int tot = btot[b];
    if (tot > BKT_CAP) tot = BKT_CAP;

    if (t < 128) ldeg[t] = 0;
    __syncthreads();

    const unsigned* gb = gcsr + (size_t)b * BKT_CAP;
    for (int i = t; i < tot; i += 512) {
        unsigned w = gb[i];
        sedge[i] = w;
        srank[i] = (unsigned short)atomicAdd(&ldeg[w >> 18], 1);
    }
    __syncthreads();

    int mydeg = (t < 128) ? ldeg[t] : 0;
    if (t < 128) ts[t] = mydeg;
    __syncthreads();
    for (int off = 1; off < 128; off <<= 1) {
        int x = (t < 128) ? ts[t] : 0;
        int y = (t >= off && t < 128) ? ts[t - off] : 0;
        __syncthreads();
        if (t < 128) ts[t] = x + y;
        __syncthreads();
    }
    if (t < 128) {
        int lbeg = ts[t] - mydeg;
        lstart[t] = lbeg;
        int node = (b << 7) + t;
        if (node < N) offs[node] = make_int2(seg0 + lbeg, seg0 + lbeg + mydeg);
        // stable descending-degree rank -> nodeord
        int r = 0;
        for (int j = 0; j < 128; j++) {
            int dj = ldeg[j];
            r += (int)((dj > mydeg) || (dj == mydeg && j < t));
        }
        nodeord[(b << 7) + r] = t;
    }
    __syncthreads();

    for (int i = t; i < tot; i += 512) {
        unsigned w = sedge[i];
        lcsr[lstart[w >> 18] + srank[i]] = (unsigned short)(w & 0xFFFFu);
    }
    __syncthreads();

    for (int i = t; i < tot; i += 512)
        csr[seg0 + i] = lcsr[i];
}

// ---------------- D3: aggregation, head-per-XCD, quad-per-edge, 4-deep ------
// grid = nbkt*2*8; head = blockIdx&7 (XCD pin). Block = 64 degree-similar
// nodes of one bucket (rank chunks interleaved across the two sub-blocks).
// Wave = 16 quads; quad = one node, lane p = feature quarter p. (R16, 89us)
#define AGG_COMPUTE(A, J)                                                      \
    {                                                                          \
        float s = fdot2(A.x, qq.x, fdot2(A.y, qq.y, 0.f));                     \
        s = qadd_xor1(s);                                                      \
        s = qadd_xor2(s);                                                      \
        float xx = clamp5(s * 0.25f);                                          \
        float sc = (e + (J) < cnt) ? __expf(xx) : 0.f;                         \
        accz += sc;                                                            \
        float2 v0 = h2f(A.z), v1 = h2f(A.w);                                   \
        av0 += sc * v0.x; av1 += sc * v0.y;                                    \
        av2 += sc * v1.x; av3 += sc * v1.y;                                    \
    }

__global__ __launch_bounds__(256) void aggregate_kernel(
    const unsigned* __restrict__ KVh,          // [H][N] 64B rows
    const uint2* __restrict__ Qr,              // [H][N] 4x uint2
    const int2* __restrict__ offs, const unsigned short* __restrict__ csr,
    const int* __restrict__ nodeord,
    float* __restrict__ out, int n)
{
    const int t = threadIdx.x;
    const int head = blockIdx.x & 7;
    const int rest = blockIdx.x >> 3;
    const int bkt = rest >> 1, sub = rest & 1;
    const int lane = t & 63;
    const int g = lane >> 2;          // quad (node slot) 0..15
    const int p = lane & 3;           // feature quarter
    const int chunk = ((t >> 6) << 1) | sub;   // interleave rank chunks

    const int spos = (bkt << 7) + (chunk << 4) + g;
    const int local = nodeord[spos];
    const int node = (bkt << 7) + local;
    const bool nvalid = (node < n);
    const int nodec = nvalid ? node : 0;

    int beg = 0, cnt = 0;
    if (nvalid) {
        int2 be = offs[node];
        beg = be.x; cnt = be.y - be.x;
    }

    const size_t hn = (size_t)head * n;
    const uint2 qq = Qr[(hn + nodec) * 4 + p];
    const char* kvb = (const char*)KVh + hn * 64;     // wave-uniform base
    const unsigned ppo = (unsigned)p << 4;            // per-lane 16B quarter

    float accz = 0.f;
    float av0 = 0.f, av1 = 0.f, av2 = 0.f, av3 = 0.f;

    const int cl = (cnt > 0) ? (cnt - 1) : 0;

    // prime: csr vector + 4 gathers for group 0, csr vector for group 1
    int np = (p < cl) ? p : cl;
    int idxA = (int)csr[beg + np];
    uint4 a0, a1, a2, a3;
    {
        unsigned j;
        j = (unsigned)QBCAST(idxA, 0); a0 = *(const uint4*)(kvb + ((j << 6) | ppo));
        j = (unsigned)QBCAST(idxA, 1); a1 = *(const uint4*)(kvb + ((j << 6) | ppo));
        j = (unsigned)QBCAST(idxA, 2); a2 = *(const uint4*)(kvb + ((j << 6) | ppo));
        j = (unsigned)QBCAST(idxA, 3); a3 = *(const uint4*)(kvb + ((j << 6) | ppo));
    }
    np = 4 + p; np = (np < cl) ? np : cl;
    int idxB = (int)csr[beg + np];

    for (int e = 0; e < cnt; e += 4) {
        // issue group g+1 gathers (indices from csr vector loaded last iter)
        unsigned j;
        uint4 b0, b1, b2, b3;
        j = (unsigned)QBCAST(idxB, 0); b0 = *(const uint4*)(kvb + ((j << 6) | ppo));
        j = (unsigned)QBCAST(idxB, 1); b1 = *(const uint4*)(kvb + ((j << 6) | ppo));
        j = (unsigned)QBCAST(idxB, 2); b2 = *(const uint4*)(kvb + ((j << 6) | ppo));
        j = (unsigned)QBCAST(idxB, 3); b3 = *(const uint4*)(kvb + ((j << 6) | ppo));
        // csr vector for group g+2
        np = e + 8 + p; np = (np < cl) ? np : cl;
        idxB = (int)csr[beg + np];

        // compute group g (loads issued last iteration: full-iter latency)
        AGG_COMPUTE(a0, 0)
        AGG_COMPUTE(a1, 1)
        AGG_COMPUTE(a2, 2)
        AGG_COMPUTE(a3, 3)

        a0 = b0; a1 = b1; a2 = b2; a3 = b3;
    }

    if (nvalid) {
        float z = accz;
        if (z == 0.f) z = 0.001f;
        float inv = 1.0f / z;
        *(float4*)(out + (size_t)node * 128 + head * 16 + p * 4) =
            make_float4(av0 * inv, av1 * inv, av2 * inv, av3 * inv);
    }
}

// ---------------------------------------------------------------------------

extern "C" void kernel_launch(void* const* d_in, const int* in_sizes, int n_in,
                              void* d_out, int out_size, void* d_ws, size_t ws_size,
                              hipStream_t stream)
{
    const float* h   = (const float*)d_in[0];
    const int*   src = (const int*)d_in[1];
    const int*   dst = (const int*)d_in[2];
    const float* p   = (const float*)d_in[3];
    const float* q   = (const float*)d_in[4];
    const float* wv  = (const float*)d_in[5];
    float* out = (float*)d_out;

    const int N = in_sizes[0] / 128;
    const int E = in_sizes[1];
    const int nbkt = (N + 127) >> BKT_SHIFT;     // 391 for N=50000 (<=512)
    const int nblk_e = (E + EPB - 1) / EPB;      // 391 for E=1.6M
    const int gemm_blocks = (N + HNODE - 1) / HNODE;   // 782

    unsigned* KV = (unsigned*)d_ws;                            // H*N*16 u32 (25.6MB)
    __half* Qh   = (__half*)(KV + (size_t)N * 128);            // H*N*16 half (12.8MB)
    unsigned* gcsr = (unsigned*)(Qh + (size_t)N * 128);        // nbkt*BKT_CAP u32 (8MB)
    int* btot    = (int*)(gcsr + (size_t)nbkt * BKT_CAP);      // nbkt
    unsigned short* csr16 = (unsigned short*)(btot + 512);     // nbkt*BKT_CAP u16 (4MB)
    int2* offs   = (int2*)(csr16 + (size_t)nbkt * BKT_CAP);    // N
    int* nodeord = (int*)(offs + N);                           // nbkt*128
    __half* Wt   = (__half*)(nodeord + (size_t)nbkt * 128);    // 3*128*128 halves

    wt_convert_kernel<<<194, 256, 0, stream>>>(q, p, wv, Wt, btot, nbkt);

    scatter_kernel<<<nblk_e, 256, 0, stream>>>(src, dst, gcsr, btot, E, nbkt);

    fine2_kernel<<<nbkt, 512, 0, stream>>>(gcsr, btot, offs, csr16, nodeord, N);

    gemm_kernel<<<gemm_blocks, 256, 0, stream>>>(h, Wt, KV, Qh, N);

    aggregate_kernel<<<nbkt * 16, 256, 0, stream>>>(
        KV, (const uint2*)Qh, offs, csr16, nodeord, (float*)out, N);
}

// Round 14
// 211.924 us; speedup vs baseline: 1.0562x; 1.0562x over previous
//
#include <hip/hip_runtime.h>
#include <hip/hip_fp16.h>

// ---------------------------------------------------------------------------
// IN=128, H=8, R=16, D=16 -> H*R = H*D = 128
// K = h @ q, Q = h @ p, V = h @ Wv   (K uses weight "q", Q uses weight "p")
// score = exp(clip((K[src]*Q[dst]).sum(r)/4, -5, 5))
// out = seg_sum(score*V[src], dst) / max(seg_sum(score,dst), eps-fixup)
//
// R13: head-per-XCD aggregation (head = blockIdx&7): 3.2MB/head fits XCD L2.
// R15/R16: node-parallel quad-per-edge aggregate: ~89us floor (validated).
// R17/R19 (FAILED): per-edge atomics (global OR LDS same-address). Banned.
// R18 (FAILED): per-head sort replication. Sort once per edge.
// R20 (=R8, BEST 214us): gcsr reservation scatter + fine2 + R16 aggregate.
// R22-R24: work-level probes of D1 all null/negative.
// R25 (split): +9.4us -> mixed overlap was worth ~9us; front-end work sums
//      to ~65us, leaving ~60-70us in DISPATCH GAPS (~10-15us each). The
//      boundaries, not the work, are the remaining front-end cost.
// R26 (this): 3 kernels + tiny memset. A = wt_convert || scatter(R10
//      direct-write). B = fine2(R8 body) || gemm (rethreaded 512thr,
//      wave-level code identical). C = aggregate (untouched). Deletes the
//      serial fine2 dispatch + one gap; memset replaces btot-zeroing.
// ---------------------------------------------------------------------------

#define EPB   4096      // edges per scatter block
#define BKT_SHIFT 7     // 128 nodes per bucket
#define BKT_CAP 5120    // bucket mean 4092 + 16 sigma

typedef _Float16 f16x8 __attribute__((ext_vector_type(8)));
typedef float    f32x4 __attribute__((ext_vector_type(4)));
typedef _Float16 hv2   __attribute__((ext_vector_type(2)));

__device__ __forceinline__ float fdot2(unsigned a, unsigned b, float c) {
#if __has_builtin(__builtin_amdgcn_fdot2)
    return __builtin_amdgcn_fdot2(__builtin_bit_cast(hv2, a),
                                  __builtin_bit_cast(hv2, b), c, false);
#else
    __half2 ah = *(__half2*)&a, bh = *(__half2*)&b;
    float2 af = __half22float2(ah), bf = __half22float2(bh);
    return c + af.x * bf.x + af.y * bf.y;
#endif
}

__device__ __forceinline__ float2 h2f(unsigned u) {
    __half2 hh = *(__half2*)&u;
    return __half22float2(hh);
}

__device__ __forceinline__ unsigned pack2(float a, float b) {
    __half2 hh = __floats2half2_rn(a, b);
    return *(unsigned*)&hh;
}

__device__ __forceinline__ float clamp5(float x) {
#if __has_builtin(__builtin_amdgcn_fmed3f)
    return __builtin_amdgcn_fmed3f(x, -5.f, 5.f);   // v_med3_f32 = clamp idiom
#else
    return fminf(fmaxf(x, -5.f), 5.f);
#endif
}

// ---- quad-scope cross-lane via DPP (VALU pipe, no LDS traffic) -------------
#if __has_builtin(__builtin_amdgcn_mov_dpp)
#define QBCAST(v, J) __builtin_amdgcn_mov_dpp((v), (J) * 0x55, 0xF, 0xF, true)
__device__ __forceinline__ float qadd_xor1(float x) {
    int y = __builtin_amdgcn_mov_dpp(__float_as_int(x), 0xB1, 0xF, 0xF, true);
    return x + __int_as_float(y);
}
__device__ __forceinline__ float qadd_xor2(float x) {
    int y = __builtin_amdgcn_mov_dpp(__float_as_int(x), 0x4E, 0xF, 0xF, true);
    return x + __int_as_float(y);
}
#else
#define QBCAST(v, J) __shfl((v), ((threadIdx.x & 63) & ~3) + (J), 64)
__device__ __forceinline__ float qadd_xor1(float x) { return x + __shfl_xor(x, 1); }
__device__ __forceinline__ float qadd_xor2(float x) { return x + __shfl_xor(x, 2); }
#endif

// ---------------- A: wt_convert blocks || scatter blocks --------------------
// wt branch (192 blocks): W[k][n] fp32 -> Wt[m][n][k] fp16.
// scatter branch (nblk_e blocks): LDS count -> ONE global atomicAdd per
// (block,bucket) reservation -> direct scattered gcsr writes (R10 body).
// btot is zeroed by a preceding hipMemsetAsync.
__global__ __launch_bounds__(256) void prep_kernel(
    const float* __restrict__ Wq, const float* __restrict__ Wp,
    const float* __restrict__ Wv, __half* __restrict__ Wt,
    const int* __restrict__ src, const int* __restrict__ dst,
    unsigned* __restrict__ gcsr, int* __restrict__ btot,
    int E, int nbkt)
{
    __shared__ int cnt[512];
    __shared__ int base_sh[512];
    const int t = threadIdx.x;

    if ((int)blockIdx.x < 192) {
        int o = blockIdx.x * 256 + t;              // 3*128*128 weights
        int m = o >> 14, rem = o & 16383;
        int nn = rem >> 7, kk = rem & 127;
        const float* W = (m == 0) ? Wq : (m == 1) ? Wp : Wv;
        Wt[o] = __float2half(W[kk * 128 + nn]);
    } else {
        int blk = blockIdx.x - 192;
        for (int i = t; i < 512; i += 256) cnt[i] = 0;
        __syncthreads();

        int4 sv[4], dv[4], rk[4];
        int base = blk * EPB + t * 4;
        #pragma unroll
        for (int r = 0; r < 4; r++) {
            int i = base + r * 1024;
            if (i + 3 < E) {
                sv[r] = *(const int4*)(src + i);
                dv[r] = *(const int4*)(dst + i);
            } else {
                int tsrc[4], tdst[4];
                for (int k = 0; k < 4; k++) {
                    int j = i + k;
                    tsrc[k] = (j < E) ? src[j] : 0;
                    tdst[k] = (j < E) ? dst[j] : -1;
                }
                sv[r] = make_int4(tsrc[0], tsrc[1], tsrc[2], tsrc[3]);
                dv[r] = make_int4(tdst[0], tdst[1], tdst[2], tdst[3]);
            }
            rk[r].x = (dv[r].x >= 0) ? atomicAdd(&cnt[dv[r].x >> BKT_SHIFT], 1) : 0;
            rk[r].y = (dv[r].y >= 0) ? atomicAdd(&cnt[dv[r].y >> BKT_SHIFT], 1) : 0;
            rk[r].z = (dv[r].z >= 0) ? atomicAdd(&cnt[dv[r].z >> BKT_SHIFT], 1) : 0;
            rk[r].w = (dv[r].w >= 0) ? atomicAdd(&cnt[dv[r].w >> BKT_SHIFT], 1) : 0;
        }
        __syncthreads();

        // reserve contiguous gcsr ranges: ONE global atomic per nonzero bucket
        for (int i = t; i < nbkt; i += 256) {
            int c = cnt[i];
            base_sh[i] = (c > 0) ? atomicAdd(&btot[i], c) : 0;
        }
        __syncthreads();

        // direct scattered writes: pos known = base_sh[bucket] + rank
        #pragma unroll
        for (int r = 0; r < 4; r++) {
            int s, d, bb, pos;
            d = dv[r].x; if (d >= 0) { s = sv[r].x; bb = d >> BKT_SHIFT; pos = base_sh[bb] + rk[r].x; if (pos < BKT_CAP) gcsr[(size_t)bb * BKT_CAP + pos] = ((unsigned)(d & 127) << 18) | (unsigned)s; }
            d = dv[r].y; if (d >= 0) { s = sv[r].y; bb = d >> BKT_SHIFT; pos = base_sh[bb] + rk[r].y; if (pos < BKT_CAP) gcsr[(size_t)bb * BKT_CAP + pos] = ((unsigned)(d & 127) << 18) | (unsigned)s; }
            d = dv[r].z; if (d >= 0) { s = sv[r].z; bb = d >> BKT_SHIFT; pos = base_sh[bb] + rk[r].z; if (pos < BKT_CAP) gcsr[(size_t)bb * BKT_CAP + pos] = ((unsigned)(d & 127) << 18) | (unsigned)s; }
            d = dv[r].w; if (d >= 0) { s = sv[r].w; bb = d >> BKT_SHIFT; pos = base_sh[bb] + rk[r].w; if (pos < BKT_CAP) gcsr[(size_t)bb * BKT_CAP + pos] = ((unsigned)(d & 127) << 18) | (unsigned)s; }
        }
    }
}

// ---------------- B: fine2 blocks || gemm blocks (512 thr) ------------------
// fine2 (blockIdx < nbkt): R8 body verbatim (coalesced gcsr read, LDS ranks,
// 128-scan -> offs, degree rank -> nodeord, LDS place, coalesced csr16).
// gemm (blockIdx >= nbkt): 128 nodes/block, 8 waves; per-wave code identical
// to R8's 256-thr version (wave w owns rows w*16..w*16+15).
__global__ __launch_bounds__(512) void gemm_fine2_kernel(
    const float* __restrict__ h, const __half* __restrict__ Wt,
    unsigned* __restrict__ KV, __half* __restrict__ Q, int n,
    const unsigned* __restrict__ gcsr, const int* __restrict__ btot,
    int2* __restrict__ offs, unsigned short* __restrict__ csr,
    int* __restrict__ nodeord, int nbkt)
{
    __shared__ __align__(16) char smem[42496];
    const int t = threadIdx.x;

    if ((int)blockIdx.x < nbkt) {
        // ------------------ fine2 branch ------------------
        unsigned* sedge = (unsigned*)smem;                       // 20480
        unsigned short* srank = (unsigned short*)(smem + 20480); // 10240
        unsigned short* lcsr  = (unsigned short*)(smem + 30720); // 10240
        int* ldeg   = (int*)(smem + 40960);                      // 512
        int* lstart = (int*)(smem + 41472);                      // 512
        int* ts     = (int*)(smem + 41984);                      // 512

        const int b = blockIdx.x;
        const int seg0 = b * BKT_CAP;

        int tot = btot[b];
        if (tot > BKT_CAP) tot = BKT_CAP;

        if (t < 128) ldeg[t] = 0;
        __syncthreads();

        const unsigned* gb = gcsr + (size_t)b * BKT_CAP;
        for (int i = t; i < tot; i += 512) {
            unsigned w = gb[i];
            sedge[i] = w;
            srank[i] = (unsigned short)atomicAdd(&ldeg[w >> 18], 1);
        }
        __syncthreads();

        int mydeg = (t < 128) ? ldeg[t] : 0;
        if (t < 128) ts[t] = mydeg;
        __syncthreads();
        for (int off = 1; off < 128; off <<= 1) {
            int x = (t < 128) ? ts[t] : 0;
            int y = (t >= off && t < 128) ? ts[t - off] : 0;
            __syncthreads();
            if (t < 128) ts[t] = x + y;
            __syncthreads();
        }
        if (t < 128) {
            int lbeg = ts[t] - mydeg;
            lstart[t] = lbeg;
            int node = (b << 7) + t;
            if (node < n) offs[node] = make_int2(seg0 + lbeg, seg0 + lbeg + mydeg);
            // stable descending-degree rank -> nodeord
            int r = 0;
            for (int j = 0; j < 128; j++) {
                int dj = ldeg[j];
                r += (int)((dj > mydeg) || (dj == mydeg && j < t));
            }
            nodeord[(b << 7) + r] = t;
        }
        __syncthreads();

        for (int i = t; i < tot; i += 512) {
            unsigned w = sedge[i];
            lcsr[lstart[w >> 18] + srank[i]] = (unsigned short)(w & 0xFFFFu);
        }
        __syncthreads();

        for (int i = t; i < tot; i += 512)
            csr[seg0 + i] = lcsr[i];
    } else {
        // ------------------ GEMM branch (MFMA 16x16x32 f16) ------------------
        _Float16* ws = (_Float16*)smem;            // 128 x 136 halves (34816B)
        const int wid = t >> 6, lane = t & 63;     // 8 waves
        const int node0 = ((int)blockIdx.x - nbkt) * 128;
        const int mrow = lane & 15, quad = lane >> 4;

        const int row = node0 + wid * 16 + mrow;
        const bool rowvalid = (row < n);
        const int rowc = rowvalid ? row : (n - 1);

        f16x8 hfr[4];
        #pragma unroll
        for (int s = 0; s < 4; s++) {
            const float4* hp = (const float4*)(h + (size_t)rowc * 128 + quad * 8 + 32 * s);
            float4 f0 = hp[0], f1 = hp[1];
            f16x8 a;
            a[0] = (_Float16)f0.x; a[1] = (_Float16)f0.y;
            a[2] = (_Float16)f0.z; a[3] = (_Float16)f0.w;
            a[4] = (_Float16)f1.x; a[5] = (_Float16)f1.y;
            a[6] = (_Float16)f1.z; a[7] = (_Float16)f1.w;
            hfr[s] = a;
        }

        f32x4 acc[3][8];
        #pragma unroll
        for (int m = 0; m < 3; m++)
            #pragma unroll
            for (int ct = 0; ct < 8; ct++) acc[m][ct] = (f32x4){0.f, 0.f, 0.f, 0.f};

        #pragma unroll
        for (int m = 0; m < 3; m++) {
            __syncthreads();
            {
                const uint4* wg = (const uint4*)(Wt + (size_t)m * 16384);
                #pragma unroll
                for (int i = 0; i < 4; i++) {
                    int idx = t * 4 + i;            // 0..2047
                    int r = idx >> 4, seg = idx & 15;
                    *(uint4*)(ws + r * 136 + seg * 8) = wg[idx];
                }
            }
            __syncthreads();
            #pragma unroll
            for (int s = 0; s < 4; s++) {
                #pragma unroll
                for (int ct = 0; ct < 8; ct++) {
                    f16x8 a = *(const f16x8*)(ws + (ct * 16 + mrow) * 136 + quad * 8 + 32 * s);
                    acc[m][ct] = __builtin_amdgcn_mfma_f32_16x16x32_f16(a, hfr[s], acc[m][ct], 0, 0, 0);
                }
            }
        }

        if (rowvalid) {
            // head-major epilogue: for MFMA tile ct, head = ct, quarter = quad
            #pragma unroll
            for (int ct = 0; ct < 8; ct++) {
                uint4 ov;
                ov.x = pack2(acc[0][ct][0], acc[0][ct][1]);   // K pair
                ov.y = pack2(acc[0][ct][2], acc[0][ct][3]);
                ov.z = pack2(acc[2][ct][0], acc[2][ct][1]);   // V pair
                ov.w = pack2(acc[2][ct][2], acc[2][ct][3]);
                *(uint4*)(KV + (((size_t)ct * n + row) << 4) + 4 * quad) = ov;
                uint2 qv;
                qv.x = pack2(acc[1][ct][0], acc[1][ct][1]);
                qv.y = pack2(acc[1][ct][2], acc[1][ct][3]);
                *(uint2*)(Q + (((size_t)ct * n + row) << 4) + 4 * quad) = qv;
            }
        }
    }
}

// ---------------- C: aggregation, head-per-XCD, quad-per-edge, 4-deep -------
// grid = nbkt*2*8; head = blockIdx&7 (XCD pin). Block = 64 degree-similar
// nodes of one bucket (rank chunks interleaved across the two sub-blocks).
// Wave = 16 quads; quad = one node, lane p = feature quarter p. (R16, 89us)
#define AGG_COMPUTE(A, J)                                                      \
    {                                                                          \
        float s = fdot2(A.x, qq.x, fdot2(A.y, qq.y, 0.f));                     \
        s = qadd_xor1(s);                                                      \
        s = qadd_xor2(s);                                                      \
        float xx = clamp5(s * 0.25f);                                          \
        float sc = (e + (J) < cnt) ? __expf(xx) : 0.f;                         \
        accz += sc;                                                            \
        float2 v0 = h2f(A.z), v1 = h2f(A.w);                                   \
        av0 += sc * v0.x; av1 += sc * v0.y;                                    \
        av2 += sc * v1.x; av3 += sc * v1.y;                                    \
    }

__global__ __launch_bounds__(256) void aggregate_kernel(
    const unsigned* __restrict__ KVh,          // [H][N] 64B rows
    const uint2* __restrict__ Qr,              // [H][N] 4x uint2
    const int2* __restrict__ offs, const unsigned short* __restrict__ csr,
    const int* __restrict__ nodeord,
    float* __restrict__ out, int n)
{
    const int t = threadIdx.x;
    const int head = blockIdx.x & 7;
    const int rest = blockIdx.x >> 3;
    const int bkt = rest >> 1, sub = rest & 1;
    const int lane = t & 63;
    const int g = lane >> 2;          // quad (node slot) 0..15
    const int p = lane & 3;           // feature quarter
    const int chunk = ((t >> 6) << 1) | sub;   // interleave rank chunks

    const int spos = (bkt << 7) + (chunk << 4) + g;
    const int local = nodeord[spos];
    const int node = (bkt << 7) + local;
    const bool nvalid = (node < n);
    const int nodec = nvalid ? node : 0;

    int beg = 0, cnt = 0;
    if (nvalid) {
        int2 be = offs[node];
        beg = be.x; cnt = be.y - be.x;
    }

    const size_t hn = (size_t)head * n;
    const uint2 qq = Qr[(hn + nodec) * 4 + p];
    const char* kvb = (const char*)KVh + hn * 64;     // wave-uniform base
    const unsigned ppo = (unsigned)p << 4;            // per-lane 16B quarter

    float accz = 0.f;
    float av0 = 0.f, av1 = 0.f, av2 = 0.f, av3 = 0.f;

    const int cl = (cnt > 0) ? (cnt - 1) : 0;

    // prime: csr vector + 4 gathers for group 0, csr vector for group 1
    int np = (p < cl) ? p : cl;
    int idxA = (int)csr[beg + np];
    uint4 a0, a1, a2, a3;
    {
        unsigned j;
        j = (unsigned)QBCAST(idxA, 0); a0 = *(const uint4*)(kvb + ((j << 6) | ppo));
        j = (unsigned)QBCAST(idxA, 1); a1 = *(const uint4*)(kvb + ((j << 6) | ppo));
        j = (unsigned)QBCAST(idxA, 2); a2 = *(const uint4*)(kvb + ((j << 6) | ppo));
        j = (unsigned)QBCAST(idxA, 3); a3 = *(const uint4*)(kvb + ((j << 6) | ppo));
    }
    np = 4 + p; np = (np < cl) ? np : cl;
    int idxB = (int)csr[beg + np];

    for (int e = 0; e < cnt; e += 4) {
        // issue group g+1 gathers (indices from csr vector loaded last iter)
        unsigned j;
        uint4 b0, b1, b2, b3;
        j = (unsigned)QBCAST(idxB, 0); b0 = *(const uint4*)(kvb + ((j << 6) | ppo));
        j = (unsigned)QBCAST(idxB, 1); b1 = *(const uint4*)(kvb + ((j << 6) | ppo));
        j = (unsigned)QBCAST(idxB, 2); b2 = *(const uint4*)(kvb + ((j << 6) | ppo));
        j = (unsigned)QBCAST(idxB, 3); b3 = *(const uint4*)(kvb + ((j << 6) | ppo));
        // csr vector for group g+2
        np = e + 8 + p; np = (np < cl) ? np : cl;
        idxB = (int)csr[beg + np];

        // compute group g (loads issued last iteration: full-iter latency)
        AGG_COMPUTE(a0, 0)
        AGG_COMPUTE(a1, 1)
        AGG_COMPUTE(a2, 2)
        AGG_COMPUTE(a3, 3)

        a0 = b0; a1 = b1; a2 = b2; a3 = b3;
    }

    if (nvalid) {
        float z = accz;
        if (z == 0.f) z = 0.001f;
        float inv = 1.0f / z;
        *(float4*)(out + (size_t)node * 128 + head * 16 + p * 4) =
            make_float4(av0 * inv, av1 * inv, av2 * inv, av3 * inv);
    }
}

// ---------------------------------------------------------------------------

extern "C" void kernel_launch(void* const* d_in, const int* in_sizes, int n_in,
                              void* d_out, int out_size, void* d_ws, size_t ws_size,
                              hipStream_t stream)
{
    const float* h   = (const float*)d_in[0];
    const int*   src = (const int*)d_in[1];
    const int*   dst = (const int*)d_in[2];
    const float* p   = (const float*)d_in[3];
    const float* q   = (const float*)d_in[4];
    const float* wv  = (const float*)d_in[5];
    float* out = (float*)d_out;

    const int N = in_sizes[0] / 128;
    const int E = in_sizes[1];
    const int nbkt = (N + 127) >> BKT_SHIFT;        // 391 for N=50000 (<=512)
    const int nblk_e = (E + EPB - 1) / EPB;         // 391 for E=1.6M
    const int gemm_blocks = (N + 127) / 128;        // 391 (128 nodes/block)

    unsigned* KV = (unsigned*)d_ws;                            // H*N*16 u32 (25.6MB)
    __half* Qh   = (__half*)(KV + (size_t)N * 128);            // H*N*16 half (12.8MB)
    unsigned* gcsr = (unsigned*)(Qh + (size_t)N * 128);        // nbkt*BKT_CAP u32 (8MB)
    int* btot    = (int*)(gcsr + (size_t)nbkt * BKT_CAP);      // 512
    unsigned short* csr16 = (unsigned short*)(btot + 512);     // nbkt*BKT_CAP u16 (4MB)
    int2* offs   = (int2*)(csr16 + (size_t)nbkt * BKT_CAP);    // N
    int* nodeord = (int*)(offs + N);                           // nbkt*128
    __half* Wt   = (__half*)(nodeord + (size_t)nbkt * 128);    // 3*128*128 halves

    hipMemsetAsync(btot, 0, 512 * sizeof(int), stream);

    prep_kernel<<<192 + nblk_e, 256, 0, stream>>>(
        q, p, wv, Wt, src, dst, gcsr, btot, E, nbkt);

    gemm_fine2_kernel<<<nbkt + gemm_blocks, 512, 0, stream>>>(
        h, Wt, KV, Qh, N, gcsr, btot, offs, csr16, nodeord, nbkt);

    aggregate_kernel<<<nbkt * 16, 256, 0, stream>>>(
        KV, (const uint2*)Qh, offs, csr16, nodeord, (float*)out, N);
}